// Round 4
// baseline (16774.307 us; speedup 1.0000x reference)
//
#include <hip/hip_runtime.h>
#include <hip/hip_cooperative_groups.h>

namespace cg = cooperative_groups;

typedef unsigned int u32;
typedef unsigned short u16;
typedef __bf16 bf16x8 __attribute__((ext_vector_type(8)));
typedef u16 us8 __attribute__((ext_vector_type(8)));
typedef float f32x4 __attribute__((ext_vector_type(4)));

#define T_N 256
#define B_N 64
#define NIN_N 256
#define H_N 2048
#define NOUT_N 256
#define BH (B_N * H_N)            // 131072
#define OUT_SZ (T_N * B_N * NOUT_N) // 4194304

struct U2 { u32 x, y; };

__device__ __forceinline__ u32 rotl32(u32 v, int r) { return (v << r) | (v >> (32 - r)); }

// JAX threefry-2x32, 20 rounds
__device__ __forceinline__ U2 tf2x32(U2 k, U2 x) {
  u32 ks0 = k.x, ks1 = k.y, ks2 = k.x ^ k.y ^ 0x1BD11BDAu;
  x.x += ks0; x.y += ks1;
#define TFR(a) x.x += x.y; x.y = rotl32(x.y,(a)); x.y ^= x.x;
  TFR(13) TFR(15) TFR(26) TFR(6)
  x.x += ks1; x.y += ks2 + 1u;
  TFR(17) TFR(29) TFR(16) TFR(24)
  x.x += ks2; x.y += ks0 + 2u;
  TFR(13) TFR(15) TFR(26) TFR(6)
  x.x += ks0; x.y += ks1 + 3u;
  TFR(17) TFR(29) TFR(16) TFR(24)
  x.x += ks1; x.y += ks2 + 4u;
  TFR(13) TFR(15) TFR(26) TFR(6)
  x.x += ks2; x.y += ks0 + 5u;
#undef TFR
  return x;
}

// JAX normal: uniform in [-1+2^-24, 1) -> sqrt(2)*erfinv (XLA f32 Giles polynomial)
__device__ __forceinline__ float jax_normal(u32 bits) {
  float f = __uint_as_float((bits >> 9) | 0x3f800000u) - 1.0f;
  const float lo = -0.99999994f;
  float u = fmaf(f, 2.0f, lo);   // (maxval-minval) rounds to exactly 2.0f
  u = fmaxf(u, lo);
  float w = -log1pf(-u * u);
  float p;
  if (w < 5.0f) {
    w = w - 2.5f;
    p =            2.81022636e-08f;
    p = fmaf(p, w, 3.43273939e-07f);
    p = fmaf(p, w, -3.5233877e-06f);
    p = fmaf(p, w, -4.39150654e-06f);
    p = fmaf(p, w, 0.00021858087f);
    p = fmaf(p, w, -0.00125372503f);
    p = fmaf(p, w, -0.00417768164f);
    p = fmaf(p, w, 0.246640727f);
    p = fmaf(p, w, 1.50140941f);
  } else {
    w = sqrtf(w) - 3.0f;
    p =            -0.000200214257f;
    p = fmaf(p, w, 0.000100950558f);
    p = fmaf(p, w, 0.00134934322f);
    p = fmaf(p, w, -0.00367342844f);
    p = fmaf(p, w, 0.00573950773f);
    p = fmaf(p, w, -0.0076224613f);
    p = fmaf(p, w, 0.00943887047f);
    p = fmaf(p, w, 1.00167406f);
    p = fmaf(p, w, 2.83297682f);
  }
  return 1.41421354f * (p * u);
}

__device__ __forceinline__ u16 f2bf(float f) {
  u32 x = __float_as_uint(f);
  u32 r = (x + 0x7FFFu + ((x >> 16) & 1u)) >> 16;
  return (u16)r;
}
__device__ __forceinline__ float bf2f(u16 b) { return __uint_as_float(((u32)b) << 16); }

__device__ __forceinline__ bf16x8 ld8(const u16* p) {
  us8 v = *reinterpret_cast<const us8*>(p);
  return __builtin_bit_cast(bf16x8, v);
}
__device__ __forceinline__ f32x4 mfma16(bf16x8 a, bf16x8 b, f32x4 c) {
  return __builtin_amdgcn_mfma_f32_16x16x32_bf16(a, b, c, 0, 0, 0);
}

// ---- Pack B-operand (W rows along n-dim): [R/16 tiles][K/32 chunks][64 lanes][8 bf16]
__global__ void __launch_bounds__(256) pack_b_kernel(const float* __restrict__ W,
    u16* __restrict__ hi, u16* __restrict__ lo, int K, int Cshift) {
  int tid = blockIdx.x * 256 + threadIdx.x;
  int lane = tid & 63;
  size_t tile = tid >> 6;
  int C = 1 << Cshift;
  int jt = (int)(tile >> Cshift), c = (int)(tile & (C - 1));
  int row = jt * 16 + (lane & 15);
  int k0 = c * 32 + (lane >> 4) * 8;
  const float* src = W + (size_t)row * K + k0;
  us8 vh, vl;
#pragma unroll
  for (int j = 0; j < 8; ++j) {
    float w = src[j];
    u16 hb = f2bf(w);
    vh[j] = hb;
    vl[j] = f2bf(w - bf2f(hb));
  }
  *reinterpret_cast<us8*>(hi + tile * 512 + lane * 8) = vh;
  *reinterpret_cast<us8*>(lo + tile * 512 + lane * 8) = vl;
}

// ---- Pack x (A-operand) per t
__global__ void __launch_bounds__(256) pack_x_kernel(const float* __restrict__ x,
    u16* __restrict__ hi, u16* __restrict__ lo) {
  int tid = blockIdx.x * 256 + threadIdx.x; // 524288
  int t = tid >> 11;
  int r = tid & 2047;
  int lane = r & 63, piece = r >> 6; // 0..31
  int c = piece >> 2, g = piece & 3;
  int row = g * 16 + (lane & 15);
  int k0 = c * 32 + (lane >> 4) * 8;
  const float* src = x + (size_t)t * (B_N * NIN_N) + (size_t)row * NIN_N + k0;
  us8 vh, vl;
#pragma unroll
  for (int j = 0; j < 8; ++j) {
    float w = src[j];
    u16 hb = f2bf(w);
    vh[j] = hb;
    vl[j] = f2bf(w - bf2f(hb));
  }
  size_t off = (size_t)t * 16384 + (size_t)piece * 512 + lane * 8;
  *reinterpret_cast<us8*>(hi + off) = vh;
  *reinterpret_cast<us8*>(lo + off) = vl;
}

// ---- Probe packs: rows all equal x[p][0][:]
__global__ void __launch_bounds__(256) pack_probe_kernel(const float* __restrict__ x,
    u16* __restrict__ p0h, u16* __restrict__ p0l, u16* __restrict__ p1h, u16* __restrict__ p1l) {
  int tid = blockIdx.x * 256 + threadIdx.x; // 4096
  int p = tid >> 11;
  int r = tid & 2047;
  int lane = r & 63, piece = r >> 6;
  int c = piece >> 2;
  int k0 = c * 32 + (lane >> 4) * 8;
  const float* src = x + (size_t)p * (B_N * NIN_N) + k0; // x[p][0][k]
  u16* hh = p ? p1h : p0h;
  u16* ll = p ? p1l : p0l;
  us8 vh, vl;
#pragma unroll
  for (int j = 0; j < 8; ++j) {
    float w = src[j];
    u16 hb = f2bf(w);
    vh[j] = hb;
    vl[j] = f2bf(w - bf2f(hb));
  }
  size_t off = (size_t)piece * 512 + lane * 8;
  *reinterpret_cast<us8*>(hh + off) = vh;
  *reinterpret_cast<us8*>(ll + off) = vl;
}

// ---- Keys (PARTITIONABLE threefry semantics, JAX >= 0.4.30 default):
//   fold_in(key, d)    = tf(key, {0, d})                      (unchanged)
//   split(key, n)[i]   = tf(key, {0, i})  (fold-like split)
//   random_bits(key,32)[i] = tf(key, {0, i}).x ^ tf(key, {0, i}).y
__global__ void setup_keys(U2* ka, U2* kb, U2* ks, u32* maxslot) {
  int i = threadIdx.x;
  U2 base{0u, 42u};
  if (i < 100) {
    U2 ki = tf2x32(base, U2{0u, (u32)i});
    ka[i] = tf2x32(ki, U2{0u, 0u});
    kb[i] = tf2x32(ki, U2{0u, 1u});
    maxslot[i] = 0u;
  }
  U2 km = tf2x32(base, U2{0u, 1000000u});
  ks[i] = tf2x32(km, U2{0u, (u32)i});   // i in 0..255
}

__global__ void __launch_bounds__(256) zero_bufs(float* h0f, u32* hx0w, u32* hx0lw) {
  int g = blockIdx.x * 256 + threadIdx.x;
  if (g < BH) h0f[g] = 0.0f;
  if (g < BH / 2) { hx0w[g] = 0u; hx0lw[g] = 0u; }
}

struct RnnParams {
  const u16 *whh_hi, *whh_lo, *wih_hi, *wih_lo;
  const u16 *xp_hi, *xp_lo;
  const u16 *xp0_hi, *xp0_lo, *xp1_hi, *xp1_lo;
  const float* bias;
  float *hf0, *hf1, *hf2;
  u16 *hx0, *hx1, *hx2, *hxA, *hxB;
  u16 *hx0l, *hx1l, *hx2l;
  const U2 *ka, *kb, *ks;
  u32* maxslot;
  float* outbuf;
};

// 128 blocks x 256 threads. block = (gb in 0..1: 32 rows) x (jt in 0..63: 32 cols).
__global__ void __launch_bounds__(256) rnn_persistent(RnnParams P) {
  cg::grid_group grid = cg::this_grid();
  __shared__ float red[4];

  const int lane = threadIdx.x & 63;
  const int wv = threadIdx.x >> 6;
  const int blk = blockIdx.x;
  const int gb = blk >> 6;
  const int jt = blk & 63;
  const int bq = wv >> 1, js = wv & 1;
  const int bqg = gb * 2 + bq;     // 16-row group 0..3
  const int jt16 = jt * 2 + js;    // 16-col tile 0..127
  const int rowb = bqg * 16;
  const int colb = jt16 * 16;
  const int col = colb + (lane & 15);
  const int q = lane >> 4;
  const float bcol = P.bias[col];

  const u16* whh_h = P.whh_hi + (size_t)jt16 * 32768 + lane * 8;
  const u16* whh_l = P.whh_lo + (size_t)jt16 * 32768 + lane * 8;
  const u16* wih_h = P.wih_hi + (size_t)jt16 * 4096 + lane * 8;
  const u16* wih_l = P.wih_lo + (size_t)jt16 * 4096 + lane * 8;

  // hi-only (main scan) or hi+lo (init, fp32-faithful) cell.
  auto cell = [&](const u16* hx_in, const u16* hx_in_lo,
                  const u16* xh, const u16* xl, U2 key,
                  const float* hprev, float* hout, u16* hxout, u16* hxout_lo,
                  const float* hcmp, u32* slot) {
    f32x4 z = {0.f,0.f,0.f,0.f};
    f32x4 a0 = z, a1 = z, a2 = z, a3 = z, a4 = z, a5 = z;
    const u16* ap = hx_in + bqg * 512 + lane * 8;
    if (hx_in_lo) {
      const u16* al_p = hx_in_lo + bqg * 512 + lane * 8;
#pragma unroll 2
      for (int c = 0; c < 64; c += 2) {
        bf16x8 ahA = ld8(ap + c * 2048);
        bf16x8 alA = ld8(al_p + c * 2048);
        bf16x8 bhA = ld8(whh_h + c * 512);
        bf16x8 blA = ld8(whh_l + c * 512);
        bf16x8 ahB = ld8(ap + (c + 1) * 2048);
        bf16x8 alB = ld8(al_p + (c + 1) * 2048);
        bf16x8 bhB = ld8(whh_h + (c + 1) * 512);
        bf16x8 blB = ld8(whh_l + (c + 1) * 512);
        a0 = mfma16(ahA, bhA, a0);
        a1 = mfma16(ahA, blA, a1);
        a2 = mfma16(alA, bhA, a2);
        a3 = mfma16(ahB, bhB, a3);
        a4 = mfma16(ahB, blB, a4);
        a5 = mfma16(alB, bhB, a5);
      }
    } else {
#pragma unroll 2
      for (int c = 0; c < 64; c += 2) {
        bf16x8 aA = ld8(ap + c * 2048);
        bf16x8 aB = ld8(ap + (c + 1) * 2048);
        bf16x8 bhA = ld8(whh_h + c * 512);
        bf16x8 blA = ld8(whh_l + c * 512);
        bf16x8 bhB = ld8(whh_h + (c + 1) * 512);
        bf16x8 blB = ld8(whh_l + (c + 1) * 512);
        a0 = mfma16(aA, bhA, a0);
        a1 = mfma16(aA, blA, a1);
        a2 = mfma16(aB, bhB, a2);
        a3 = mfma16(aB, blB, a3);
      }
    }
    const u16* xph = xh + bqg * 512 + lane * 8;
    const u16* xpl = xl + bqg * 512 + lane * 8;
#pragma unroll
    for (int c = 0; c < 8; ++c) {
      bf16x8 ah = ld8(xph + c * 2048);
      bf16x8 al = ld8(xpl + c * 2048);
      bf16x8 bh = ld8(wih_h + c * 512);
      bf16x8 bl = ld8(wih_l + c * 512);
      a0 = mfma16(ah, bh, a0);
      a1 = mfma16(ah, bl, a1);
      a2 = mfma16(al, bh, a2);
    }
    f32x4 acc = ((a0 + a1) + (a2 + a3)) + (a4 + a5);
    // epilogue: C/D layout col=lane&15, row=(lane>>4)*4+reg
    float lmax = 0.0f;
#pragma unroll
    for (int r = 0; r < 4; ++r) {
      int row = rowb + q * 4 + r;
      u32 idx = (u32)row * H_N + (u32)col;
      U2 o = tf2x32(key, U2{0u, idx});       // partitionable: per-element ctr (0, idx)
      float nz = jax_normal(o.x ^ o.y);      // 32-bit draw = x ^ y
      float pre = acc[r] + bcol + 0.15811388300841897f * nz;
      float hp = hprev[idx];
      float hn = 0.8f * hp + 0.2f * fmaxf(pre, 0.0f);
      hout[idx] = hn;
      int cH = col >> 5, qq = (col >> 3) & 3, jj = col & 7;
      u32 xoff = ((cH * 4 + (row >> 4)) * 64 + qq * 16 + (row & 15)) * 8 + jj;
      u16 hb = f2bf(hn);
      hxout[xoff] = hb;
      if (hxout_lo) hxout_lo[xoff] = f2bf(hn - bf2f(hb));
      if (hcmp) lmax = fmaxf(lmax, fabsf(hn - hcmp[idx]));
    }
    if (slot) {
#pragma unroll
      for (int off = 32; off >= 1; off >>= 1)
        lmax = fmaxf(lmax, __shfl_down(lmax, off));
      if (lane == 0) red[wv] = lmax;
      __syncthreads();
      if (threadIdx.x == 0) {
        float m = fmaxf(fmaxf(red[0], red[1]), fmaxf(red[2], red[3]));
        atomicMax(slot, __float_as_uint(m));
      }
    }
  };

  // ---- init loop (fp32-faithful via hi+lo activations)
  float* hfs[3] = {P.hf0, P.hf1, P.hf2};
  u16* hxs[3] = {P.hx0, P.hx1, P.hx2};
  u16* hxls[3] = {P.hx0l, P.hx1l, P.hx2l};
  int i0 = 0, i1 = 1, i2 = 2;
  int stable = 0;
#pragma unroll 1
  for (int it = 0; it < 100; ++it) {
    cell(hxs[i0], hxls[i0], P.xp0_hi, P.xp0_lo, P.ka[it],
         hfs[i0], hfs[i1], hxs[i1], hxls[i1], nullptr, nullptr);
    grid.sync();
    cell(hxs[i1], hxls[i1], P.xp1_hi, P.xp1_lo, P.kb[it],
         hfs[i1], hfs[i2], hxs[i2], hxls[i2], hfs[i0], P.maxslot + it);
    grid.sync();
    u32 mb = __hip_atomic_load(P.maxslot + it, __ATOMIC_RELAXED, __HIP_MEMORY_SCOPE_AGENT);
    bool close = (__uint_as_float(mb) <= 0.1f);
    if (close) {
      if (++stable >= 4) break;  // trigger: h0 stays = hfs[i0]
    } else stable = 0;
    int tmp = i0; i0 = i2; i2 = tmp; // h0 <- h2
  }

  // ---- main scan: hidden goes straight into d_out
  float* hidden = P.outbuf + OUT_SZ;
#pragma unroll 1
  for (int t = 0; t < T_N; ++t) {
    const u16* hin = (t == 0) ? hxs[i0] : (((t - 1) & 1) ? P.hxB : P.hxA);
    u16* hxo = (t & 1) ? P.hxB : P.hxA;
    const float* hprev = (t == 0) ? hfs[i0] : hidden + (size_t)(t - 1) * BH;
    cell(hin, nullptr, P.xp_hi + (size_t)t * 16384, P.xp_lo + (size_t)t * 16384, P.ks[t],
         hprev, hidden + (size_t)t * BH, hxo, nullptr, nullptr, nullptr);
    if (t != T_N - 1) grid.sync();
  }
}

// ---- output GEMM: out[M=16384][256] = hidden(bf16) @ Wout^T (hi+lo)
__global__ void __launch_bounds__(256) out_gemm(const float* __restrict__ hidden,
    const u16* __restrict__ wo_hi, const u16* __restrict__ wo_lo, float* __restrict__ out) {
  int lane = threadIdx.x & 63, wv = threadIdx.x >> 6;
  int mb = blockIdx.x * 64 + wv * 16;
  int arow = mb + (lane & 15);
  int q = lane >> 4;
  f32x4 acc[16];
#pragma unroll
  for (int n = 0; n < 16; ++n) acc[n] = {0.f, 0.f, 0.f, 0.f};
  const float* ap = hidden + (size_t)arow * H_N + q * 8;
#pragma unroll 2
  for (int c = 0; c < 64; ++c) {
    const float4* a4 = reinterpret_cast<const float4*>(ap + c * 32);
    float4 f0 = a4[0], f1 = a4[1];
    us8 av;
    av[0] = f2bf(f0.x); av[1] = f2bf(f0.y); av[2] = f2bf(f0.z); av[3] = f2bf(f0.w);
    av[4] = f2bf(f1.x); av[5] = f2bf(f1.y); av[6] = f2bf(f1.z); av[7] = f2bf(f1.w);
    bf16x8 a = __builtin_bit_cast(bf16x8, av);
#pragma unroll
    for (int n = 0; n < 16; ++n) {
      bf16x8 bh = ld8(wo_hi + ((size_t)(n * 64 + c) * 64 + lane) * 8);
      bf16x8 bl = ld8(wo_lo + ((size_t)(n * 64 + c) * 64 + lane) * 8);
      acc[n] = mfma16(a, bh, acc[n]);
      acc[n] = mfma16(a, bl, acc[n]);
    }
  }
#pragma unroll
  for (int n = 0; n < 16; ++n)
#pragma unroll
    for (int r = 0; r < 4; ++r)
      out[(size_t)(mb + q * 4 + r) * NOUT_N + n * 16 + (lane & 15)] = acc[n][r];
}

extern "C" void kernel_launch(void* const* d_in, const int* in_sizes, int n_in,
                              void* d_out, int out_size, void* d_ws, size_t ws_size,
                              hipStream_t stream) {
  const float* x = (const float*)d_in[0];
  const float* W_ih = (const float*)d_in[1];
  const float* W_hh = (const float*)d_in[2];
  const float* bias = (const float*)d_in[3];
  const float* W_out = (const float*)d_in[4];
  float* out = (float*)d_out;

  char* ws = (char*)d_ws;
  size_t off = 0;
  auto alloc = [&](size_t bytes) -> void* {
    void* p = ws + off;
    off += (bytes + 255) & ~(size_t)255;
    return p;
  };
  u16* whh_hi = (u16*)alloc(8388608);
  u16* whh_lo = (u16*)alloc(8388608);
  u16* wih_hi = (u16*)alloc(1048576);
  u16* wih_lo = (u16*)alloc(1048576);
  u16* wout_hi = (u16*)alloc(1048576);
  u16* wout_lo = (u16*)alloc(1048576);
  u16* xp_hi = (u16*)alloc(8388608);
  u16* xp_lo = (u16*)alloc(8388608);
  u16* xp0_hi = (u16*)alloc(32768);
  u16* xp0_lo = (u16*)alloc(32768);
  u16* xp1_hi = (u16*)alloc(32768);
  u16* xp1_lo = (u16*)alloc(32768);
  float* hf0 = (float*)alloc(524288);
  float* hf1 = (float*)alloc(524288);
  float* hf2 = (float*)alloc(524288);
  u16* hx0 = (u16*)alloc(262144);
  u16* hx1 = (u16*)alloc(262144);
  u16* hx2 = (u16*)alloc(262144);
  u16* hxA = (u16*)alloc(262144);
  u16* hxB = (u16*)alloc(262144);
  u16* hx0l = (u16*)alloc(262144);
  u16* hx1l = (u16*)alloc(262144);
  u16* hx2l = (u16*)alloc(262144);
  U2* ka = (U2*)alloc(800);
  U2* kb = (U2*)alloc(800);
  U2* ks = (U2*)alloc(2048);
  u32* maxslot = (u32*)alloc(400);

  hipLaunchKernelGGL(pack_b_kernel, dim3(2048), dim3(256), 0, stream, W_hh, whh_hi, whh_lo, 2048, 6);
  hipLaunchKernelGGL(pack_b_kernel, dim3(256), dim3(256), 0, stream, W_ih, wih_hi, wih_lo, 256, 3);
  hipLaunchKernelGGL(pack_b_kernel, dim3(256), dim3(256), 0, stream, W_out, wout_hi, wout_lo, 2048, 6);
  hipLaunchKernelGGL(pack_x_kernel, dim3(2048), dim3(256), 0, stream, x, xp_hi, xp_lo);
  hipLaunchKernelGGL(pack_probe_kernel, dim3(16), dim3(256), 0, stream, x, xp0_hi, xp0_lo, xp1_hi, xp1_lo);
  hipLaunchKernelGGL(setup_keys, dim3(1), dim3(256), 0, stream, ka, kb, ks, maxslot);
  hipLaunchKernelGGL(zero_bufs, dim3(512), dim3(256), 0, stream, hf0, (u32*)hx0, (u32*)hx0l);

  RnnParams P;
  P.whh_hi = whh_hi; P.whh_lo = whh_lo; P.wih_hi = wih_hi; P.wih_lo = wih_lo;
  P.xp_hi = xp_hi; P.xp_lo = xp_lo;
  P.xp0_hi = xp0_hi; P.xp0_lo = xp0_lo; P.xp1_hi = xp1_hi; P.xp1_lo = xp1_lo;
  P.bias = bias;
  P.hf0 = hf0; P.hf1 = hf1; P.hf2 = hf2;
  P.hx0 = hx0; P.hx1 = hx1; P.hx2 = hx2; P.hxA = hxA; P.hxB = hxB;
  P.hx0l = hx0l; P.hx1l = hx1l; P.hx2l = hx2l;
  P.ka = ka; P.kb = kb; P.ks = ks;
  P.maxslot = maxslot;
  P.outbuf = out;

  void* kargs[] = {(void*)&P};
  hipLaunchCooperativeKernel((const void*)rnn_persistent, dim3(128), dim3(256), kargs, 0, stream);

  hipLaunchKernelGGL(out_gemm, dim3(256), dim3(256), 0, stream, out + OUT_SZ, wout_hi, wout_lo, out);
}